// Round 1
// baseline (1219.339 us; speedup 1.0000x reference)
//
#include <hip/hip_runtime.h>

#define BB 64
#define SS 2048
#define HH 128

// 64-term partial dot: hrow points at 64 contiguous floats in LDS (wave-uniform
// up to 2 addresses -> free broadcast), w is 64 register-resident weights.
__device__ __forceinline__ float dot64(const float* __restrict__ hrow,
                                       const float* __restrict__ w) {
  const float4* h4 = (const float4*)hrow;
  float a0 = 0.f, a1 = 0.f, a2 = 0.f, a3 = 0.f;
#pragma unroll
  for (int i = 0; i < 16; i += 4) {
    float4 v0 = h4[i + 0], v1 = h4[i + 1], v2 = h4[i + 2], v3 = h4[i + 3];
    a0 = fmaf(v0.x, w[4 * i + 0], a0);  a0 = fmaf(v0.y, w[4 * i + 1], a0);
    a0 = fmaf(v0.z, w[4 * i + 2], a0);  a0 = fmaf(v0.w, w[4 * i + 3], a0);
    a1 = fmaf(v1.x, w[4 * i + 4], a1);  a1 = fmaf(v1.y, w[4 * i + 5], a1);
    a1 = fmaf(v1.z, w[4 * i + 6], a1);  a1 = fmaf(v1.w, w[4 * i + 7], a1);
    a2 = fmaf(v2.x, w[4 * i + 8], a2);  a2 = fmaf(v2.y, w[4 * i + 9], a2);
    a2 = fmaf(v2.z, w[4 * i + 10], a2); a2 = fmaf(v2.w, w[4 * i + 11], a2);
    a3 = fmaf(v3.x, w[4 * i + 12], a3); a3 = fmaf(v3.y, w[4 * i + 13], a3);
    a3 = fmaf(v3.z, w[4 * i + 14], a3); a3 = fmaf(v3.w, w[4 * i + 15], a3);
  }
  return (a0 + a1) + (a2 + a3);
}

// out[r][j] = in[r][:] @ W[:][j] + bias[j], K=N=128. One WG = 32 rows.
// thread: j = tid>>1 (output col), half = tid&1 (k-half). W column half in
// 64 VGPRs; partner combine via shfl_xor(1) (lanes 2j, 2j+1 same wave).
__global__ __launch_bounds__(256) void gemm128(const float* __restrict__ in,
                                               const float* __restrict__ W,
                                               const float* __restrict__ bias,
                                               float* __restrict__ out) {
  __shared__ __align__(16) float xt[32 * 128];  // 16 KB staging tile
  const int tid = threadIdx.x;
  const int j = tid >> 1, half = tid & 1;

  float w[64];
  const float* wcol = W + (half * 64) * 128 + j;
#pragma unroll
  for (int k = 0; k < 64; ++k) w[k] = wcol[k * 128];
  const float bj = bias[j];

  const long row0 = (long)blockIdx.x * 32;
  const float4* g4 = (const float4*)(in + row0 * 128);
  float4* l4 = (float4*)xt;
#pragma unroll
  for (int i = 0; i < 4; ++i) l4[tid + 256 * i] = g4[tid + 256 * i];
  __syncthreads();

  float* outp = out + row0 * 128 + j;
#pragma unroll 2
  for (int r = 0; r < 32; ++r) {
    float acc = dot64(xt + r * 128 + half * 64, w);
    acc += __shfl_xor(acc, 1);
    if (half == 0) outp[r * 128] = acc + bj;  // even lanes: j contiguous -> coalesced
  }
}

// Sequential recurrence: h_t = relu(tanh(xi_t + h_{t-1} @ Wh)).
// One WG per batch row. h double-buffered in LDS (1 barrier/step).
// h_t overwrites xi[b][t][:] in-place (consumed by its own writer pair; the
// prefetch of that address happened PF steps earlier) -> one ws buffer.
__global__ __launch_bounds__(256) void rnn_rec(float* __restrict__ xi,
                                               const float* __restrict__ Wh) {
  __shared__ __align__(16) float hbuf[2][128];
  const int tid = threadIdx.x;
  const int j = tid >> 1, half = tid & 1;

  float w[64];
  const float* wcol = Wh + (half * 64) * 128 + j;
#pragma unroll
  for (int k = 0; k < 64; ++k) w[k] = wcol[k * 128];

  if (tid < 128) hbuf[0][tid] = 0.0f;  // h0 = 0

  float* xb = xi + (size_t)blockIdx.x * SS * HH + j;

  constexpr int PF = 8;  // prefetch depth: ~8 steps * ~250cyc > 900cyc HBM latency
  float pre[PF];
#pragma unroll
  for (int p = 0; p < PF; ++p) pre[p] = xb[p * HH];
  __syncthreads();

  for (int t0 = 0; t0 < SS; t0 += PF) {
#pragma unroll
    for (int p = 0; p < PF; ++p) {
      const int t = t0 + p;
      float acc = dot64(&hbuf[t & 1][half * 64], w);
      acc += __shfl_xor(acc, 1);
      const float v = pre[p] + acc;
      // tanh(v) = 1 - 2/(exp2(v*2*log2e)+1); safe at +-inf (no NaN)
      const float e = __builtin_amdgcn_exp2f(v * 2.8853900817779268f);
      const float hn = fmaxf(1.0f - 2.0f * __builtin_amdgcn_rcpf(e + 1.0f), 0.0f);
      if (half == 0) {
        hbuf[(t & 1) ^ 1][j] = hn;  // write buffer for step t+1
        xb[t * HH] = hn;            // hs for phase 3 (overwrites consumed xi)
      }
      const int tn = t + PF;
      pre[p] = (tn < SS) ? xb[tn * HH] : 0.0f;
      __syncthreads();
    }
  }
}

extern "C" void kernel_launch(void* const* d_in, const int* in_sizes, int n_in,
                              void* d_out, int out_size, void* d_ws, size_t ws_size,
                              hipStream_t stream) {
  const float* x  = (const float*)d_in[0];
  const float* Wi = (const float*)d_in[1];
  const float* Wh = (const float*)d_in[2];
  const float* b  = (const float*)d_in[3];
  const float* Wo = (const float*)d_in[4];
  const float* bo = (const float*)d_in[5];
  float* y  = (float*)d_out;
  float* xi = (float*)d_ws;  // 64 MB: holds xi, then overwritten in-place with hs

  gemm128<<<(BB * SS) / 32, 256, 0, stream>>>(x, Wi, b, xi);
  rnn_rec<<<BB, 256, 0, stream>>>(xi, Wh);
  gemm128<<<(BB * SS) / 32, 256, 0, stream>>>(xi, Wo, bo, y);
}

// Round 2
// 1192.179 us; speedup vs baseline: 1.0228x; 1.0228x over previous
//
#include <hip/hip_runtime.h>

#define BB 64
#define SS 2048
#define HH 128

// CK-style LDS-only barrier: waits DS ops (lgkmcnt) but NOT outstanding
// global loads/stores (vmcnt) -- __syncthreads() drains vmcnt(0) and would
// put the per-step global prefetch/store on the critical path.
__device__ __forceinline__ void lds_barrier() {
  asm volatile("s_waitcnt lgkmcnt(0)\n\ts_barrier" ::: "memory");
}

// 64-term partial dot: hrow points at 64 contiguous floats in LDS, w is 64
// register-resident weights. Within a wave only 2 distinct hrow addresses
// (even/odd lanes) -> broadcast; caller guarantees they land on disjoint
// bank groups (pad +4 floats between halves).
__device__ __forceinline__ float dot64(const float* __restrict__ hrow,
                                       const float* __restrict__ w) {
  const float4* h4 = (const float4*)hrow;
  float a0 = 0.f, a1 = 0.f, a2 = 0.f, a3 = 0.f;
#pragma unroll
  for (int i = 0; i < 16; i += 4) {
    float4 v0 = h4[i + 0], v1 = h4[i + 1], v2 = h4[i + 2], v3 = h4[i + 3];
    a0 = fmaf(v0.x, w[4 * i + 0], a0);  a0 = fmaf(v0.y, w[4 * i + 1], a0);
    a0 = fmaf(v0.z, w[4 * i + 2], a0);  a0 = fmaf(v0.w, w[4 * i + 3], a0);
    a1 = fmaf(v1.x, w[4 * i + 4], a1);  a1 = fmaf(v1.y, w[4 * i + 5], a1);
    a1 = fmaf(v1.z, w[4 * i + 6], a1);  a1 = fmaf(v1.w, w[4 * i + 7], a1);
    a2 = fmaf(v2.x, w[4 * i + 8], a2);  a2 = fmaf(v2.y, w[4 * i + 9], a2);
    a2 = fmaf(v2.z, w[4 * i + 10], a2); a2 = fmaf(v2.w, w[4 * i + 11], a2);
    a3 = fmaf(v3.x, w[4 * i + 12], a3); a3 = fmaf(v3.y, w[4 * i + 13], a3);
    a3 = fmaf(v3.z, w[4 * i + 14], a3); a3 = fmaf(v3.w, w[4 * i + 15], a3);
  }
  return (a0 + a1) + (a2 + a3);
}

// out[r][j] = in[r][:] @ W[:][j] + bias[j], K=N=128. One WG = 32 rows.
__global__ __launch_bounds__(256) void gemm128(const float* __restrict__ in,
                                               const float* __restrict__ W,
                                               const float* __restrict__ bias,
                                               float* __restrict__ out) {
  __shared__ __align__(16) float xt[32 * 128];  // 16 KB staging tile
  const int tid = threadIdx.x;
  const int j = tid >> 1, half = tid & 1;

  float w[64];
  const float* wcol = W + (half * 64) * 128 + j;
#pragma unroll
  for (int k = 0; k < 64; ++k) w[k] = wcol[k * 128];
  const float bj = bias[j];

  const long row0 = (long)blockIdx.x * 32;
  const float4* g4 = (const float4*)(in + row0 * 128);
  float4* l4 = (float4*)xt;
#pragma unroll
  for (int i = 0; i < 4; ++i) l4[tid + 256 * i] = g4[tid + 256 * i];
  __syncthreads();

  float* outp = out + row0 * 128 + j;
#pragma unroll 2
  for (int r = 0; r < 32; ++r) {
    float acc = dot64(xt + r * 128 + half * 64, w);
    acc += __shfl_xor(acc, 1);
    if (half == 0) outp[r * 128] = acc + bj;  // even lanes: j contiguous -> coalesced
  }
}

// Sequential recurrence: h_t = relu(tanh(xi_t + h_{t-1} @ Wh)).
// One WG per batch row, 4 waves, K half-split (thread = (col j, k-half)).
// h double-buffered in LDS; the two K-halves are padded 4 floats apart so the
// wave's 2 distinct ds_read_b128 addresses hit disjoint bank groups
// (R1: SQ_LDS_BANK_CONFLICT=3.35e7 from the unpadded 64-float offset).
__global__ __launch_bounds__(256) void rnn_rec(float* __restrict__ xi,
                                               const float* __restrict__ Wh) {
  __shared__ __align__(16) float hbuf[2][136];  // halves at [0..63] and [68..131]
  const int tid = threadIdx.x;
  const int j = tid >> 1, half = tid & 1;
  const int jj = (j < 64) ? j : (j + 4);  // padded write slot

  float w[64];
  const float* wcol = Wh + (half * 64) * 128 + j;
#pragma unroll
  for (int k = 0; k < 64; ++k) w[k] = wcol[k * 128];

  if (tid < 136) hbuf[0][tid] = 0.0f;  // h0 = 0 (incl. pad)

  float* xb = xi + (size_t)blockIdx.x * SS * HH + j;

  constexpr int PF = 8;  // prefetch depth: consumed 8 steps (~2500 cyc) later
  float pre[PF];
#pragma unroll
  for (int p = 0; p < PF; ++p) pre[p] = xb[p * HH];
  __syncthreads();

  for (int t0 = 0; t0 < SS; t0 += PF) {
#pragma unroll
    for (int p = 0; p < PF; ++p) {
      const int t = t0 + p;
      float acc = dot64(&hbuf[t & 1][half * 68], w);
      acc += __shfl_xor(acc, 1);
      const float v = pre[p] + acc;
      // tanh(v) = 1 - 2/(exp2(2v*log2e)+1); safe at +-inf
      const float e = __builtin_amdgcn_exp2f(v * 2.8853900817779268f);
      const float hn = fmaxf(1.0f - 2.0f * __builtin_amdgcn_rcpf(e + 1.0f), 0.0f);
      if (half == 0) {
        hbuf[(t & 1) ^ 1][jj] = hn;  // buffer for step t+1
        xb[t * HH] = hn;             // hs for phase 3 (fire-and-forget)
      }
      const int tn = t + PF;
      pre[p] = (tn < SS) ? xb[tn * HH] : 0.0f;
      lds_barrier();  // lgkm-only: global ops stay off the critical path
    }
  }
}

extern "C" void kernel_launch(void* const* d_in, const int* in_sizes, int n_in,
                              void* d_out, int out_size, void* d_ws, size_t ws_size,
                              hipStream_t stream) {
  const float* x  = (const float*)d_in[0];
  const float* Wi = (const float*)d_in[1];
  const float* Wh = (const float*)d_in[2];
  const float* b  = (const float*)d_in[3];
  const float* Wo = (const float*)d_in[4];
  const float* bo = (const float*)d_in[5];
  float* y  = (float*)d_out;
  float* xi = (float*)d_ws;  // 64 MB: holds xi, then overwritten in-place with hs

  gemm128<<<(BB * SS) / 32, 256, 0, stream>>>(x, Wi, b, xi);
  rnn_rec<<<BB, 256, 0, stream>>>(xi, Wh);
  gemm128<<<(BB * SS) / 32, 256, 0, stream>>>(xi, Wo, bo, y);
}

// Round 3
// 1102.218 us; speedup vs baseline: 1.1063x; 1.0816x over previous
//
#include <hip/hip_runtime.h>

#define BB 64
#define SS 2048
#define HH 128

// LDS-only barrier: drains DS ops (lgkmcnt) but NOT outstanding global
// loads/stores -- keeps per-step prefetch/stores off the critical path.
__device__ __forceinline__ void lds_barrier() {
  asm volatile("s_waitcnt lgkmcnt(0)\n\ts_barrier" ::: "memory");
}

// ---------------------------------------------------------------------------
// GEMM: out[row][j] = in[row][:] @ W[:][j] + bias[j], K=N=128.
// Tile 128 rows x 128 cols per WG; 256 threads; thread = 8 rows x 8 cols
// (64 accumulators) so each LDS b128 read feeds 16+ FMAs (R2 post-mortem:
// O=1 made the old gemm LDS-pipe-bound at ~164us vs 27us FMA floor).
// W staged with +4-float pad per 32 cols to spread the cg*8 column stride
// across bank groups.
// ---------------------------------------------------------------------------
__global__ __launch_bounds__(256) void gemm128v2(const float* __restrict__ in,
                                                 const float* __restrict__ W,
                                                 const float* __restrict__ bias,
                                                 float* __restrict__ out) {
  __shared__ __align__(16) float xls[128 * 128];   // 64 KB
  __shared__ __align__(16) float wls[128 * 140];   // 70 KB (padded rows)
  const int t = threadIdx.x;
  const long row0 = (long)blockIdx.x * 128;

  // stage x-tile: 128 rows x 128 cols, straight float4 copy (coalesced)
  {
    const float4* g4 = (const float4*)(in + row0 * 128);
    float4* l4 = (float4*)xls;
#pragma unroll
    for (int it = 0; it < 16; ++it) l4[t + 256 * it] = g4[t + 256 * it];
  }
  // stage W with bank-spread pad: W[k][j] -> wls[k*140 + j + 4*(j>>5)]
  {
#pragma unroll
    for (int it = 0; it < 16; ++it) {
      const int fidx = (t + 256 * it) * 4;
      const int k = fidx >> 7, j = fidx & 127;
      const float4 v = *(const float4*)(W + fidx);
      *(float4*)(wls + k * 140 + j + 4 * (j >> 5)) = v;
    }
  }
  __syncthreads();

  const int rg = t >> 4, cg = t & 15;  // 16 row-groups x 16 col-groups
  const float* xrow = xls + (rg * 8) * 128;
  const float* wcol = wls + cg * 8 + 4 * (cg >> 2);

  float4 acc0[8], acc1[8];
#pragma unroll
  for (int r = 0; r < 8; ++r) {
    acc0[r] = make_float4(0.f, 0.f, 0.f, 0.f);
    acc1[r] = make_float4(0.f, 0.f, 0.f, 0.f);
  }

  for (int k = 0; k < 128; k += 4) {
    float4 xv[8];
#pragma unroll
    for (int r = 0; r < 8; ++r) xv[r] = *(const float4*)(xrow + r * 128 + k);
#pragma unroll
    for (int kk = 0; kk < 4; ++kk) {
      const float* wr = wcol + (k + kk) * 140;
      const float4 w0 = *(const float4*)(wr);
      const float4 w1 = *(const float4*)(wr + 4);
#pragma unroll
      for (int r = 0; r < 8; ++r) {
        const float xs = (kk == 0) ? xv[r].x : (kk == 1) ? xv[r].y
                       : (kk == 2) ? xv[r].z : xv[r].w;
        acc0[r].x = fmaf(xs, w0.x, acc0[r].x);
        acc0[r].y = fmaf(xs, w0.y, acc0[r].y);
        acc0[r].z = fmaf(xs, w0.z, acc0[r].z);
        acc0[r].w = fmaf(xs, w0.w, acc0[r].w);
        acc1[r].x = fmaf(xs, w1.x, acc1[r].x);
        acc1[r].y = fmaf(xs, w1.y, acc1[r].y);
        acc1[r].z = fmaf(xs, w1.z, acc1[r].z);
        acc1[r].w = fmaf(xs, w1.w, acc1[r].w);
      }
    }
  }

  const float4 b0 = *(const float4*)(bias + cg * 8);
  const float4 b1 = *(const float4*)(bias + cg * 8 + 4);
  float* op = out + (row0 + rg * 8) * 128 + cg * 8;
#pragma unroll
  for (int r = 0; r < 8; ++r) {
    float4 o0, o1;
    o0.x = acc0[r].x + b0.x; o0.y = acc0[r].y + b0.y;
    o0.z = acc0[r].z + b0.z; o0.w = acc0[r].w + b0.w;
    o1.x = acc1[r].x + b1.x; o1.y = acc1[r].y + b1.y;
    o1.z = acc1[r].z + b1.z; o1.w = acc1[r].w + b1.w;
    *(float4*)(op + r * 128) = o0;
    *(float4*)(op + r * 128 + 4) = o1;
  }
}

// ---------------------------------------------------------------------------
// Recurrence: h_t = relu(tanh(xi_t + h_{t-1} @ Wh)). One WG per batch row.
// Thread = (jg = tid>>2: 2 output cols, kg = tid&3: 32-k range) -> O=2,
// halving LDS fan-out vs R2 (32 b128 wave-instrs/step instead of 64, which
// was the measured ~768cyc/step LDS-pipe floor). kg lives in lane bits 0-1
// so the cross-range reduction is two DPP-able __shfl_xor, no LDS phase,
// still one lgkm-only barrier per step.
// h layout: 4 ranges of 32 floats at stride 36 -> the 4 wave-distinct b128
// addresses land on disjoint 4-bank windows (kg*36 mod 32 = {0,4,8,12}).
// ---------------------------------------------------------------------------
__global__ __launch_bounds__(256) void rnn_rec(float* __restrict__ xi,
                                               const float* __restrict__ Wh) {
  __shared__ __align__(16) float hbuf[2][144];
  const int tid = threadIdx.x;
  const int jg = tid >> 2;   // 0..63
  const int kg = tid & 3;    // 0..3
  const int j2 = jg * 2;

  // weights: w2[i] = Wh[kg*32+i][j2..j2+1] -> 64 VGPRs
  float2 w2[32];
  const float* wp = Wh + (kg * 32) * HH + j2;
#pragma unroll
  for (int i = 0; i < 32; ++i) w2[i] = *(const float2*)(wp + i * HH);

  if (tid < 144) hbuf[0][tid] = 0.0f;  // h0 = 0 (incl. pads)

  float* xb = xi + (size_t)blockIdx.x * SS * HH + j2;

  constexpr int PF = 8;  // consumed ~8 steps (~2500 cyc) after issue
  float2 pre[PF];
  if (kg == 0) {
#pragma unroll
    for (int p = 0; p < PF; ++p) pre[p] = *(const float2*)(xb + p * HH);
  }
  __syncthreads();

  const int hoff = 36 * (j2 >> 5) + (j2 & 31);  // write slot for h[j2..j2+1]

  for (int t0 = 0; t0 < SS; t0 += PF) {
#pragma unroll
    for (int p = 0; p < PF; ++p) {
      const int t = t0 + p;
      const float4* h4 = (const float4*)(hbuf[t & 1] + kg * 36);
      float2 acc[4];
#pragma unroll
      for (int c = 0; c < 4; ++c) acc[c] = make_float2(0.f, 0.f);
#pragma unroll
      for (int q = 0; q < 8; ++q) {
        const float4 hv = h4[q];
        const float2 wa = w2[4 * q + 0], wb = w2[4 * q + 1];
        const float2 wc = w2[4 * q + 2], wd = w2[4 * q + 3];
        const int c = q & 3;  // 4 independent dep chains per component
        acc[c].x = fmaf(hv.x, wa.x, acc[c].x);
        acc[c].x = fmaf(hv.y, wb.x, acc[c].x);
        acc[c].x = fmaf(hv.z, wc.x, acc[c].x);
        acc[c].x = fmaf(hv.w, wd.x, acc[c].x);
        acc[c].y = fmaf(hv.x, wa.y, acc[c].y);
        acc[c].y = fmaf(hv.y, wb.y, acc[c].y);
        acc[c].y = fmaf(hv.z, wc.y, acc[c].y);
        acc[c].y = fmaf(hv.w, wd.y, acc[c].y);
      }
      float sx = (acc[0].x + acc[1].x) + (acc[2].x + acc[3].x);
      float sy = (acc[0].y + acc[1].y) + (acc[2].y + acc[3].y);
      // reduce over kg = lane bits 0-1 (butterfly; DPP quad_perm, no LDS)
      sx += __shfl_xor(sx, 1);
      sx += __shfl_xor(sx, 2);
      sy += __shfl_xor(sy, 1);
      sy += __shfl_xor(sy, 2);
      if (kg == 0) {
        const float vx = pre[p].x + sx;
        const float vy = pre[p].y + sy;
        // tanh(v) = 1 - 2/(exp2(2v*log2e)+1); safe at +-inf
        const float ex = __builtin_amdgcn_exp2f(vx * 2.8853900817779268f);
        const float ey = __builtin_amdgcn_exp2f(vy * 2.8853900817779268f);
        float2 hn;
        hn.x = fmaxf(1.0f - 2.0f * __builtin_amdgcn_rcpf(ex + 1.0f), 0.0f);
        hn.y = fmaxf(1.0f - 2.0f * __builtin_amdgcn_rcpf(ey + 1.0f), 0.0f);
        *(float2*)(&hbuf[(t & 1) ^ 1][hoff]) = hn;  // h for step t+1
        *(float2*)(xb + t * HH) = hn;               // hs for phase 3
        const int tn = t + PF;
        if (tn < SS) pre[p] = *(const float2*)(xb + tn * HH);
      }
      lds_barrier();
    }
  }
}

extern "C" void kernel_launch(void* const* d_in, const int* in_sizes, int n_in,
                              void* d_out, int out_size, void* d_ws, size_t ws_size,
                              hipStream_t stream) {
  const float* x  = (const float*)d_in[0];
  const float* Wi = (const float*)d_in[1];
  const float* Wh = (const float*)d_in[2];
  const float* b  = (const float*)d_in[3];
  const float* Wo = (const float*)d_in[4];
  const float* bo = (const float*)d_in[5];
  float* y  = (float*)d_out;
  float* xi = (float*)d_ws;  // 64 MB: holds xi, then overwritten in-place with hs

  gemm128v2<<<(BB * SS) / 128, 256, 0, stream>>>(x, Wi, b, xi);
  rnn_rec<<<BB, 256, 0, stream>>>(xi, Wh);
  gemm128v2<<<(BB * SS) / 128, 256, 0, stream>>>(xi, Wo, bo, y);
}